// Round 1
// baseline (7439.787 us; speedup 1.0000x reference)
//
#include <hip/hip_runtime.h>
#include <math.h>

// Problem constants (see reference): B=1024, T=50, D=64, H=1024, FH=128, L=2
#define BATCH   1024
#define HID     1024
#define DIN     64
#define TKNOTS  50
#define FHID    128
#define NSTEPS  50
#define DT_C      0.02f
#define SQRT_DT_C 0.1414213562373095f   // sqrt(0.02)

#define BM 64
#define BN 64
#define BK 32

#define MODE_LIN      0
#define MODE_LIPSWISH 1
#define MODE_RELU     2

// C[M,N] = act(A @ B + bias). N is split at `nhalf`: blocks with n>=nhalf use
// B1/bias1 (with local column n-nhalf) and offset A by a_off_hi columns.
// This lets one kernel compute [y@Wf0 | y@Wg0] and [hf@Wf1 | hg@Wg1].
__global__ __launch_bounds__(256) void gemm_k(
    const float* __restrict__ A, int lda, int a_off_hi,
    const float* __restrict__ B0, const float* __restrict__ B1, int ldb,
    const float* __restrict__ bias0, const float* __restrict__ bias1,
    float* __restrict__ C, int ldc, int K, int nhalf, int mode)
{
  __shared__ float As[BK][BM];   // A-tile, transposed: As[k][m]
  __shared__ float Bs[BK][BN];   // B-tile: Bs[k][n]

  const int t   = threadIdx.x;
  const int m0  = blockIdx.y * BM;
  const int cn0 = blockIdx.x * BN;   // output column base (original numbering)
  int n0 = cn0;
  const float* Bm   = B0;
  const float* bias = bias0;
  if (n0 >= nhalf) { n0 -= nhalf; Bm = B1; bias = bias1; A += a_off_hi; }

  // global-load assignments (2 float4 each for A and B per K-iter)
  const int ar = t >> 3;           // 0..31  (A row within tile)
  const int ac = (t & 7) << 2;     // 0,4,...,28 (A col within tile)
  const int br = t >> 4;           // 0..15  (B row within tile)
  const int bc = (t & 15) << 2;    // 0..60  (B col within tile)

  // per-thread output fragment position
  const int i0 = (t >> 4) << 2;    // 0..60
  const int j0 = (t & 15) << 2;    // 0..60

  float acc[4][4];
#pragma unroll
  for (int r = 0; r < 4; ++r)
#pragma unroll
    for (int c = 0; c < 4; ++c) acc[r][c] = 0.0f;

  for (int k0 = 0; k0 < K; k0 += BK) {
    const float4 a0 = *(const float4*)(A + (size_t)(m0 + ar)      * lda + k0 + ac);
    const float4 a1 = *(const float4*)(A + (size_t)(m0 + ar + 32) * lda + k0 + ac);
    const float4 b0 = *(const float4*)(Bm + (size_t)(k0 + br)      * ldb + n0 + bc);
    const float4 b1 = *(const float4*)(Bm + (size_t)(k0 + br + 16) * ldb + n0 + bc);

    __syncthreads();   // previous iteration's LDS reads must finish
    As[ac + 0][ar] = a0.x; As[ac + 1][ar] = a0.y;
    As[ac + 2][ar] = a0.z; As[ac + 3][ar] = a0.w;
    As[ac + 0][ar + 32] = a1.x; As[ac + 1][ar + 32] = a1.y;
    As[ac + 2][ar + 32] = a1.z; As[ac + 3][ar + 32] = a1.w;
    *(float4*)&Bs[br][bc]      = b0;
    *(float4*)&Bs[br + 16][bc] = b1;
    __syncthreads();

#pragma unroll
    for (int kk = 0; kk < BK; ++kk) {
      const float4 av = *(const float4*)&As[kk][i0];
      const float4 bv = *(const float4*)&Bs[kk][j0];
      const float a_[4] = {av.x, av.y, av.z, av.w};
      const float b_[4] = {bv.x, bv.y, bv.z, bv.w};
#pragma unroll
      for (int r = 0; r < 4; ++r)
#pragma unroll
        for (int c = 0; c < 4; ++c)
          acc[r][c] = fmaf(a_[r], b_[c], acc[r][c]);
    }
  }

  // epilogue: bias + activation, float4 stores
#pragma unroll
  for (int r = 0; r < 4; ++r) {
    float4 v;
    float* vp = &v.x;
#pragma unroll
    for (int c = 0; c < 4; ++c) {
      float x = acc[r][c] + bias[n0 + j0 + c];
      if (mode == MODE_LIPSWISH)      x = 0.909f * x / (1.0f + expf(-x));
      else if (mode == MODE_RELU)     x = fmaxf(x, 0.0f);
      vp[c] = x;
    }
    *(float4*)(C + (size_t)(m0 + i0 + r) * ldc + cn0 + j0) = v;
  }
}

// y0[b,j] = sum_d coeffs[b,0,d] * initial_w[d,j] + initial_b[j]
__global__ __launch_bounds__(256) void y0_k(
    const float* __restrict__ coeffs, const float* __restrict__ w,
    const float* __restrict__ b, float* __restrict__ y)
{
  __shared__ float c[DIN];
  const int bi = blockIdx.x;
  if (threadIdx.x < DIN) c[threadIdx.x] = coeffs[(size_t)bi * (TKNOTS * DIN) + threadIdx.x];
  __syncthreads();
#pragma unroll
  for (int r = 0; r < 4; ++r) {
    const int j = threadIdx.x + r * 256;
    float s = b[j];
#pragma unroll 8
    for (int d = 0; d < DIN; ++d) s = fmaf(c[d], w[(size_t)d * HID + j], s);
    y[(size_t)bi * HID + j] = s;
  }
}

// y[b,j] += DT*drift[b,j] + SQRT_DT*dw[b,j]*diff[b,j];  d = [drift | diff] (ldc=2048)
__global__ __launch_bounds__(256) void update_y_k(
    float* __restrict__ y, const float* __restrict__ d, const float* __restrict__ dwk)
{
  const int i   = blockIdx.x * 256 + threadIdx.x;   // float4 id, 0..262143
  const int row = i >> 8;
  const int c4  = (i & 255) << 2;
  float4 yv = *(float4*)(y + (size_t)row * HID + c4);
  const float4 dr = *(const float4*)(d + (size_t)row * 2048 + c4);
  const float4 df = *(const float4*)(d + (size_t)row * 2048 + HID + c4);
  const float4 wv = *(const float4*)(dwk + (size_t)row * HID + c4);
  yv.x = fmaf(DT_C, dr.x, fmaf(SQRT_DT_C * wv.x, df.x, yv.x));
  yv.y = fmaf(DT_C, dr.y, fmaf(SQRT_DT_C * wv.y, df.y, yv.y));
  yv.z = fmaf(DT_C, dr.z, fmaf(SQRT_DT_C * wv.z, df.z, yv.z));
  yv.w = fmaf(DT_C, dr.w, fmaf(SQRT_DT_C * wv.w, df.w, yv.w));
  *(float4*)(y + (size_t)row * HID + c4) = yv;
}

// tvec[j] = emb_b[j] + sum_k (k/127) * emb_w[128+k, j]   (the constant t-branch
// of the concat([z,t]) @ emb_w, identical for every batch row)
__global__ __launch_bounds__(256) void tvec_k(
    const float* __restrict__ emb_w, const float* __restrict__ emb_b,
    float* __restrict__ tv)
{
  const int j = blockIdx.x * 256 + threadIdx.x;   // 0..1023
  float s = emb_b[j];
#pragma unroll 8
  for (int k = 0; k < FHID; ++k)
    s = fmaf((float)k * (1.0f / 127.0f), emb_w[(size_t)(FHID + k) * HID + j], s);
  tv[j] = s;
}

extern "C" void kernel_launch(void* const* d_in, const int* in_sizes, int n_in,
                              void* d_out, int out_size, void* d_ws, size_t ws_size,
                              hipStream_t stream) {
  const float* coeffs    = (const float*)d_in[0];
  // d_in[1] = times (unused: f/g are time-independent; y0 uses knot 0 only)
  const float* dw        = (const float*)d_in[2];
  const float* f_ws      = (const float*)d_in[3];
  const float* f_bs      = (const float*)d_in[4];
  const float* g_ws      = (const float*)d_in[5];
  const float* g_bs      = (const float*)d_in[6];
  const float* initial_w = (const float*)d_in[7];
  const float* initial_b = (const float*)d_in[8];
  const float* lin_in_w  = (const float*)d_in[9];
  const float* lin_in_b  = (const float*)d_in[10];
  const float* emb_w     = (const float*)d_in[11];
  const float* emb_b     = (const float*)d_in[12];
  const float* samp_w    = (const float*)d_in[13];
  const float* samp_b    = (const float*)d_in[14];
  float* out = (float*)d_out;

  // workspace layout (floats): y[1M] h[2M] d[2M] z1[128K] z2[1M] tv[1K]  ~26MB
  float* ws = (float*)d_ws;
  float* y  = ws;
  float* h  = y  + (size_t)BATCH * HID;
  float* dd = h  + (size_t)BATCH * 2 * HID;
  float* z1 = dd + (size_t)BATCH * 2 * HID;
  float* z2 = z1 + (size_t)BATCH * FHID;
  float* tv = z2 + (size_t)BATCH * HID;

  const int NOSPLIT = 1 << 30;

  // y0 = coeffs[:,0,:] @ initial_w + initial_b
  y0_k<<<BATCH, 256, 0, stream>>>(coeffs, initial_w, initial_b, y);

  const dim3 gStep(2 * HID / BN, BATCH / BM);   // (32, 16)
  for (int k = 0; k < NSTEPS; ++k) {
    // h = lipswish(y @ [Wf0 | Wg0] + [bf0 | bg0])      -> [1024, 2048]
    gemm_k<<<gStep, 256, 0, stream>>>(
        y, HID, 0,
        f_ws, g_ws, HID,
        f_bs, g_bs,
        h, 2 * HID, HID, HID, MODE_LIPSWISH);
    // d = [hf @ Wf1 + bf1 | hg @ Wg1 + bg1]            -> [1024, 2048]
    gemm_k<<<gStep, 256, 0, stream>>>(
        h, 2 * HID, HID,
        f_ws + (size_t)HID * HID, g_ws + (size_t)HID * HID, HID,
        f_bs + HID, g_bs + HID,
        dd, 2 * HID, HID, HID, MODE_LIN);
    // y += DT*drift + SQRT_DT*dw_k*diff
    update_y_k<<<(BATCH * HID / 4) / 256, 256, 0, stream>>>(
        y, dd, dw + (size_t)k * BATCH * HID);
  }

  // z1 = relu(y @ lin_in_w + lin_in_b)                 -> [1024, 128]
  gemm_k<<<dim3(FHID / BN, BATCH / BM), 256, 0, stream>>>(
      y, HID, 0, lin_in_w, nullptr, FHID, lin_in_b, nullptr,
      z1, FHID, HID, NOSPLIT, MODE_RELU);

  // tv[j] = emb_b[j] + sum_k t_k * emb_w[128+k, j]
  tvec_k<<<HID / 256, 256, 0, stream>>>(emb_w, emb_b, tv);

  // z2 = relu(z1 @ emb_w[0:128,:] + tv)                -> [1024, 1024]
  gemm_k<<<dim3(HID / BN, BATCH / BM), 256, 0, stream>>>(
      z1, FHID, 0, emb_w, nullptr, HID, tv, nullptr,
      z2, HID, FHID, NOSPLIT, MODE_RELU);

  // out = z2 @ samp_w + samp_b                         -> [1024, 128]
  gemm_k<<<dim3(FHID / BN, BATCH / BM), 256, 0, stream>>>(
      z2, HID, 0, samp_w, nullptr, FHID, samp_b, nullptr,
      out, FHID, HID, NOSPLIT, MODE_LIN);
}

// Round 2
// 2736.047 us; speedup vs baseline: 2.7192x; 2.7192x over previous
//
#include <hip/hip_runtime.h>
#include <math.h>

typedef _Float16 f16;
typedef _Float16 f16x8 __attribute__((ext_vector_type(8)));
typedef float f32x4 __attribute__((ext_vector_type(4)));

#define BATCH   1024
#define HID     1024
#define DIN     64
#define TKNOTS  50
#define FHID    128
#define NSTEPS  50
#define DT_C      0.02f
#define SQRT_DT_C 0.1414213562373095f
#define LO_SCALE  2048.0f
#define INV_LO    4.8828125e-4f   // 1/2048

__device__ __forceinline__ void gload16(const f16* g, const f16* l) {
  __builtin_amdgcn_global_load_lds((const __attribute__((address_space(1))) unsigned int*)g,
                                   (__attribute__((address_space(3))) unsigned int*)l, 16, 0, 0);
}

__device__ __forceinline__ void split_f32(float x, f16& hi, f16& lo) {
  hi = (f16)x;
  lo = (f16)((x - (float)hi) * LO_SCALE);
}

// ---------------------------------------------------------------------------
// fp16x3 split GEMM: C[1024 x 2048] = act(A @ B + bias)
// A given as hi/lo f16 pair, row-major [1024][lda]; for n>=1024 blocks A is
// offset by aoff columns (gemm2: picks h_g half). B given as hi/lo pair in
// transposed layout Bt[n][k] ([2048][1024]). bias: col<1024 -> bias0[col],
// else bias1[col-1024].
// MODE 0: write fp32 Cf.  MODE 1: lipswish, write split f16 pair Ch/Cl.
// Tiles: 64x64, BK=32, 256 thr (4 waves 2x2, wave-tile 32x32), double-buffered
// LDS (32 KB static), global_load_lds staging with inverse-swizzled source and
// swizzled ds_read (sigma(r) = ((r>>1)&3)<<4  -> exact 2-way = free).
// ---------------------------------------------------------------------------
template<int MODE>
__global__ __launch_bounds__(256) void gemm3_k(
    const f16* __restrict__ Ah, const f16* __restrict__ Al, int lda, int aoff,
    const f16* __restrict__ Bh, const f16* __restrict__ Bl,
    const float* __restrict__ bias0, const float* __restrict__ bias1,
    float* __restrict__ Cf, f16* __restrict__ Ch, f16* __restrict__ Cl)
{
  __shared__ __align__(16) char smem[32768];   // 2 buffers x 16 KB

  const int tid = threadIdx.x;

  // XCD-aware block swizzle (512 = 8 * 64, bijective): each XCD gets 4
  // contiguous n-slices x all 16 m-slices -> B working set ~1 MB + A ~4 MB.
  const int bid = blockIdx.x;
  const int r   = ((bid & 7) << 6) | (bid >> 3);
  const int m0  = (r & 15) << 6;       // 0..960
  const int n0  = (r >> 4) << 6;       // 0..1984

  const f16* Ah_p = Ah + (n0 >= HID ? aoff : 0);
  const f16* Al_p = Al + (n0 >= HID ? aoff : 0);

  // ---- staging source pointers (linear LDS dest o=tid*16; element that
  // belongs there is row sr = o>>6, halfs col sc = ((o&63) ^ sigma(sr))>>1) ----
  const int sr = tid >> 2;                                   // 0..63
  const int sc = (((tid & 3) << 4) ^ (((sr >> 1) & 3) << 4)) >> 1;  // 0..31
  const f16* gAh = Ah_p + (size_t)(m0 + sr) * lda + sc;
  const f16* gAl = Al_p + (size_t)(m0 + sr) * lda + sc;
  const f16* gBh = Bh   + (size_t)(n0 + sr) * HID + sc;
  const f16* gBl = Bl   + (size_t)(n0 + sr) * HID + sc;

  // ---- fragment read addressing ----
  const int lane = tid & 63;
  const int wid  = tid >> 6;
  const int wm   = wid >> 1;           // 0..1
  const int wn   = wid & 1;            // 0..1
  const int fr   = lane & 15;
  const int fg   = lane >> 4;          // 0..3
  const int sig  = ((fr >> 1) & 3) << 4;
  const int kb   = (fg << 4) ^ sig;    // swizzled k-slot byte within 64B row
  const int ra0  = (wm * 32 + fr) * 64;
  const int ra1  = ra0 + 16 * 64;
  const int rb0  = (wn * 32 + fr) * 64;
  const int rb1  = rb0 + 16 * 64;

  f32x4 acc1[2][2] = {};
  f32x4 acc2[2][2] = {};

  // prologue: stage buffer 0 (k=0)
  {
    char* db = smem + (tid << 4);
    gload16(gAh, (const f16*)(db));
    gload16(gAl, (const f16*)(db + 4096));
    gload16(gBh, (const f16*)(db + 8192));
    gload16(gBl, (const f16*)(db + 12288));
  }
  __syncthreads();

  int cur = 0;
  for (int kt = 0; kt < HID / 32; ++kt) {
    if (kt < HID / 32 - 1) {
      const int ko = (kt + 1) << 5;    // halfs
      char* db = smem + ((cur ^ 1) * 16384) + (tid << 4);
      gload16(gAh + ko, (const f16*)(db));
      gload16(gAl + ko, (const f16*)(db + 4096));
      gload16(gBh + ko, (const f16*)(db + 8192));
      gload16(gBl + ko, (const f16*)(db + 12288));
    }

    const char* cb = smem + cur * 16384;
    f16x8 ah0 = *(const f16x8*)(cb + ra0 + kb);
    f16x8 ah1 = *(const f16x8*)(cb + ra1 + kb);
    f16x8 al0 = *(const f16x8*)(cb + 4096 + ra0 + kb);
    f16x8 al1 = *(const f16x8*)(cb + 4096 + ra1 + kb);
    f16x8 bh0 = *(const f16x8*)(cb + 8192 + rb0 + kb);
    f16x8 bh1 = *(const f16x8*)(cb + 8192 + rb1 + kb);
    f16x8 bl0 = *(const f16x8*)(cb + 12288 + rb0 + kb);
    f16x8 bl1 = *(const f16x8*)(cb + 12288 + rb1 + kb);

    acc1[0][0] = __builtin_amdgcn_mfma_f32_16x16x32_f16(ah0, bh0, acc1[0][0], 0, 0, 0);
    acc1[0][1] = __builtin_amdgcn_mfma_f32_16x16x32_f16(ah0, bh1, acc1[0][1], 0, 0, 0);
    acc1[1][0] = __builtin_amdgcn_mfma_f32_16x16x32_f16(ah1, bh0, acc1[1][0], 0, 0, 0);
    acc1[1][1] = __builtin_amdgcn_mfma_f32_16x16x32_f16(ah1, bh1, acc1[1][1], 0, 0, 0);
    acc2[0][0] = __builtin_amdgcn_mfma_f32_16x16x32_f16(ah0, bl0, acc2[0][0], 0, 0, 0);
    acc2[0][1] = __builtin_amdgcn_mfma_f32_16x16x32_f16(ah0, bl1, acc2[0][1], 0, 0, 0);
    acc2[1][0] = __builtin_amdgcn_mfma_f32_16x16x32_f16(ah1, bl0, acc2[1][0], 0, 0, 0);
    acc2[1][1] = __builtin_amdgcn_mfma_f32_16x16x32_f16(ah1, bl1, acc2[1][1], 0, 0, 0);
    acc2[0][0] = __builtin_amdgcn_mfma_f32_16x16x32_f16(al0, bh0, acc2[0][0], 0, 0, 0);
    acc2[0][1] = __builtin_amdgcn_mfma_f32_16x16x32_f16(al0, bh1, acc2[0][1], 0, 0, 0);
    acc2[1][0] = __builtin_amdgcn_mfma_f32_16x16x32_f16(al1, bh0, acc2[1][0], 0, 0, 0);
    acc2[1][1] = __builtin_amdgcn_mfma_f32_16x16x32_f16(al1, bh1, acc2[1][1], 0, 0, 0);

    __syncthreads();   // drains global_load_lds (vmcnt0) + lds reads, then barrier
    cur ^= 1;
  }

  // epilogue
#pragma unroll
  for (int fm = 0; fm < 2; ++fm) {
#pragma unroll
    for (int fn = 0; fn < 2; ++fn) {
      const int row = m0 + wm * 32 + fm * 16 + fg * 4;
      const int col = n0 + wn * 32 + fn * 16 + fr;
      const float bs = (col < HID) ? bias0[col] : bias1[col - HID];
#pragma unroll
      for (int rr = 0; rr < 4; ++rr) {
        float v = acc1[fm][fn][rr] + acc2[fm][fn][rr] * INV_LO + bs;
        if (MODE == 1) {
          const float x = 0.909f * v / (1.0f + expf(-v));
          f16 hi, lo; split_f32(x, hi, lo);
          Ch[(size_t)(row + rr) * 2048 + col] = hi;
          Cl[(size_t)(row + rr) * 2048 + col] = lo;
        } else {
          Cf[(size_t)(row + rr) * 2048 + col] = v;
        }
      }
    }
  }
}

// ---------------------------------------------------------------------------
// weight prep: split+transpose W[k][n] (fp32) -> Bt_hi/lo[n][k] (f16).
// blockIdx.z selects {f_ws l0, g_ws l0, f_ws l1, g_ws l1}.
// ---------------------------------------------------------------------------
__global__ __launch_bounds__(256) void split_transpose_k(
    const float* __restrict__ f_ws, const float* __restrict__ g_ws,
    f16* __restrict__ Bt0h, f16* __restrict__ Bt0l,
    f16* __restrict__ Bt1h, f16* __restrict__ Bt1l)
{
  __shared__ float t[32][33];
  const int z = blockIdx.z;
  const float* src = (z & 1) ? g_ws : f_ws;
  if (z >= 2) src += (size_t)HID * HID;
  f16* dh = (z >= 2) ? Bt1h : Bt0h;
  f16* dl = (z >= 2) ? Bt1l : Bt0l;
  const int nb = (z & 1) ? HID : 0;

  const int tx = threadIdx.x;        // 0..31
  const int ty = threadIdx.y;        // 0..7
  const int k0 = blockIdx.y * 32;
  const int n0 = blockIdx.x * 32;
#pragma unroll
  for (int i = 0; i < 4; ++i)
    t[ty + i * 8][tx] = src[(size_t)(k0 + ty + i * 8) * HID + n0 + tx];
  __syncthreads();
#pragma unroll
  for (int i = 0; i < 4; ++i) {
    const int n = n0 + ty + i * 8;
    const int k = k0 + tx;
    const float v = t[tx][ty + i * 8];
    f16 hi, lo; split_f32(v, hi, lo);
    dh[(size_t)(nb + n) * HID + k] = hi;
    dl[(size_t)(nb + n) * HID + k] = lo;
  }
}

// y0[b,j] = coeffs[b,0,:] @ initial_w + initial_b   (+ split outputs)
__global__ __launch_bounds__(256) void y0_k(
    const float* __restrict__ coeffs, const float* __restrict__ w,
    const float* __restrict__ b, float* __restrict__ y,
    f16* __restrict__ yh, f16* __restrict__ yl)
{
  __shared__ float c[DIN];
  const int bi = blockIdx.x;
  if (threadIdx.x < DIN) c[threadIdx.x] = coeffs[(size_t)bi * (TKNOTS * DIN) + threadIdx.x];
  __syncthreads();
#pragma unroll
  for (int rr = 0; rr < 4; ++rr) {
    const int j = threadIdx.x + rr * 256;
    float s = b[j];
#pragma unroll 8
    for (int d = 0; d < DIN; ++d) s = fmaf(c[d], w[(size_t)d * HID + j], s);
    y[(size_t)bi * HID + j] = s;
    f16 hi, lo; split_f32(s, hi, lo);
    yh[(size_t)bi * HID + j] = hi;
    yl[(size_t)bi * HID + j] = lo;
  }
}

// y += DT*drift + SQRT_DT*dw*diff;  dd = [drift | diff] fp32 [1024][2048];
// also refresh the y hi/lo split for the next step's gemm1.
__global__ __launch_bounds__(256) void update_y_k(
    float* __restrict__ y, f16* __restrict__ yh, f16* __restrict__ yl,
    const float* __restrict__ dd, const float* __restrict__ dwk)
{
  const int i   = blockIdx.x * 256 + threadIdx.x;   // float4 id
  const int row = i >> 8;
  const int c4  = (i & 255) << 2;
  float4 yv = *(float4*)(y + (size_t)row * HID + c4);
  const float4 dr = *(const float4*)(dd + (size_t)row * 2048 + c4);
  const float4 df = *(const float4*)(dd + (size_t)row * 2048 + HID + c4);
  const float4 wv = *(const float4*)(dwk + (size_t)row * HID + c4);
  yv.x = fmaf(DT_C, dr.x, fmaf(SQRT_DT_C * wv.x, df.x, yv.x));
  yv.y = fmaf(DT_C, dr.y, fmaf(SQRT_DT_C * wv.y, df.y, yv.y));
  yv.z = fmaf(DT_C, dr.z, fmaf(SQRT_DT_C * wv.z, df.z, yv.z));
  yv.w = fmaf(DT_C, dr.w, fmaf(SQRT_DT_C * wv.w, df.w, yv.w));
  *(float4*)(y + (size_t)row * HID + c4) = yv;
  const float vals[4] = {yv.x, yv.y, yv.z, yv.w};
#pragma unroll
  for (int t = 0; t < 4; ++t) {
    f16 hi, lo; split_f32(vals[t], hi, lo);
    yh[(size_t)row * HID + c4 + t] = hi;
    yl[(size_t)row * HID + c4 + t] = lo;
  }
}

// ---------------- fp32 decoder GEMM (round-1 kernel, small share) ----------
#define BM 64
#define BN 64
#define BK 32
#define MODE_LIN  0
#define MODE_RELU 2

__global__ __launch_bounds__(256) void gemm_k(
    const float* __restrict__ A, int lda,
    const float* __restrict__ B0, int ldb,
    const float* __restrict__ bias0,
    float* __restrict__ C, int ldc, int K, int mode)
{
  __shared__ float As[BK][BM];
  __shared__ float Bs[BK][BN];
  const int t  = threadIdx.x;
  const int m0 = blockIdx.y * BM;
  const int n0 = blockIdx.x * BN;
  const int ar = t >> 3, ac = (t & 7) << 2;
  const int br = t >> 4, bc = (t & 15) << 2;
  const int i0 = (t >> 4) << 2, j0 = (t & 15) << 2;
  float acc[4][4];
#pragma unroll
  for (int rr = 0; rr < 4; ++rr)
#pragma unroll
    for (int c = 0; c < 4; ++c) acc[rr][c] = 0.0f;

  for (int k0 = 0; k0 < K; k0 += BK) {
    const float4 a0 = *(const float4*)(A + (size_t)(m0 + ar)      * lda + k0 + ac);
    const float4 a1 = *(const float4*)(A + (size_t)(m0 + ar + 32) * lda + k0 + ac);
    const float4 b0 = *(const float4*)(B0 + (size_t)(k0 + br)      * ldb + n0 + bc);
    const float4 b1 = *(const float4*)(B0 + (size_t)(k0 + br + 16) * ldb + n0 + bc);
    __syncthreads();
    As[ac + 0][ar] = a0.x; As[ac + 1][ar] = a0.y; As[ac + 2][ar] = a0.z; As[ac + 3][ar] = a0.w;
    As[ac + 0][ar + 32] = a1.x; As[ac + 1][ar + 32] = a1.y;
    As[ac + 2][ar + 32] = a1.z; As[ac + 3][ar + 32] = a1.w;
    *(float4*)&Bs[br][bc] = b0;
    *(float4*)&Bs[br + 16][bc] = b1;
    __syncthreads();
#pragma unroll
    for (int kk = 0; kk < BK; ++kk) {
      const float4 av = *(const float4*)&As[kk][i0];
      const float4 bv = *(const float4*)&Bs[kk][j0];
      const float a_[4] = {av.x, av.y, av.z, av.w};
      const float b_[4] = {bv.x, bv.y, bv.z, bv.w};
#pragma unroll
      for (int rr = 0; rr < 4; ++rr)
#pragma unroll
        for (int c = 0; c < 4; ++c)
          acc[rr][c] = fmaf(a_[rr], b_[c], acc[rr][c]);
    }
  }
#pragma unroll
  for (int rr = 0; rr < 4; ++rr) {
    float4 v; float* vp = &v.x;
#pragma unroll
    for (int c = 0; c < 4; ++c) {
      float x = acc[rr][c] + bias0[n0 + j0 + c];
      if (mode == MODE_RELU) x = fmaxf(x, 0.0f);
      vp[c] = x;
    }
    *(float4*)(C + (size_t)(m0 + i0 + rr) * ldc + n0 + j0) = v;
  }
}

__global__ __launch_bounds__(256) void tvec_k(
    const float* __restrict__ emb_w, const float* __restrict__ emb_b,
    float* __restrict__ tv)
{
  const int j = blockIdx.x * 256 + threadIdx.x;
  float s = emb_b[j];
#pragma unroll 8
  for (int k = 0; k < FHID; ++k)
    s = fmaf((float)k * (1.0f / 127.0f), emb_w[(size_t)(FHID + k) * HID + j], s);
  tv[j] = s;
}

// ---------------------------------------------------------------------------
extern "C" void kernel_launch(void* const* d_in, const int* in_sizes, int n_in,
                              void* d_out, int out_size, void* d_ws, size_t ws_size,
                              hipStream_t stream) {
  const float* coeffs    = (const float*)d_in[0];
  const float* dw        = (const float*)d_in[2];
  const float* f_ws      = (const float*)d_in[3];
  const float* f_bs      = (const float*)d_in[4];
  const float* g_ws      = (const float*)d_in[5];
  const float* g_bs      = (const float*)d_in[6];
  const float* initial_w = (const float*)d_in[7];
  const float* initial_b = (const float*)d_in[8];
  const float* lin_in_w  = (const float*)d_in[9];
  const float* lin_in_b  = (const float*)d_in[10];
  const float* emb_w     = (const float*)d_in[11];
  const float* emb_b     = (const float*)d_in[12];
  const float* samp_w    = (const float*)d_in[13];
  const float* samp_b    = (const float*)d_in[14];
  float* out = (float*)d_out;

  // workspace carve (bytes)
  char* ws = (char*)d_ws;
  f16*   Bt0h = (f16*)(ws);                       // 4 MB  [2048][1024]
  f16*   Bt0l = (f16*)(ws + (4u << 20));
  f16*   Bt1h = (f16*)(ws + (8u << 20));
  f16*   Bt1l = (f16*)(ws + (12u << 20));
  f16*   yh   = (f16*)(ws + (16u << 20));         // 2 MB
  f16*   yl   = (f16*)(ws + (18u << 20));
  f16*   hh   = (f16*)(ws + (20u << 20));         // 4 MB  [1024][2048]
  f16*   hl   = (f16*)(ws + (24u << 20));
  float* y    = (float*)(ws + (28u << 20));       // 4 MB
  float* dd   = (float*)(ws + (32u << 20));       // 8 MB  [1024][2048]
  float* z1   = (float*)(ws + (40u << 20));       // 512 KB
  float* z2   = (float*)(ws + (41u << 20));       // 4 MB
  float* tv   = (float*)(ws + (45u << 20));       // 4 KB

  // weight split+transpose (runs every launch; in-graph)
  split_transpose_k<<<dim3(HID / 32, HID / 32, 4), dim3(32, 8), 0, stream>>>(
      f_ws, g_ws, Bt0h, Bt0l, Bt1h, Bt1l);

  y0_k<<<BATCH, 256, 0, stream>>>(coeffs, initial_w, initial_b, y, yh, yl);

  for (int k = 0; k < NSTEPS; ++k) {
    // h = lipswish(y @ [Wf0|Wg0] + bias)  -> split f16 pair [1024][2048]
    gemm3_k<1><<<512, 256, 0, stream>>>(
        yh, yl, HID, 0, Bt0h, Bt0l, f_bs, g_bs, nullptr, hh, hl);
    // dd = [h_f @ Wf1 + bf1 | h_g @ Wg1 + bg1]  fp32 [1024][2048]
    gemm3_k<0><<<512, 256, 0, stream>>>(
        hh, hl, 2048, HID, Bt1h, Bt1l, f_bs + HID, g_bs + HID, dd, nullptr, nullptr);
    update_y_k<<<(BATCH * HID / 4) / 256, 256, 0, stream>>>(
        y, yh, yl, dd, dw + (size_t)k * BATCH * HID);
  }

  // decoder (fp32, small)
  gemm_k<<<dim3(FHID / BN, BATCH / BM), 256, 0, stream>>>(
      y, HID, lin_in_w, FHID, lin_in_b, z1, FHID, HID, MODE_RELU);
  tvec_k<<<HID / 256, 256, 0, stream>>>(emb_w, emb_b, tv);
  gemm_k<<<dim3(HID / BN, BATCH / BM), 256, 0, stream>>>(
      z1, FHID, emb_w, HID, tv, z2, HID, FHID, MODE_RELU);
  gemm_k<<<dim3(FHID / BN, BATCH / BM), 256, 0, stream>>>(
      z2, HID, samp_w, FHID, samp_b, out, FHID, HID, MODE_LIN);
}